// Round 5
// baseline (415.352 us; speedup 1.0000x reference)
//
#include <hip/hip_runtime.h>

// SpikingNeuronLayer fused producer/consumer, R5:
//   blocks 0..511   : GEMM workers, 2 blocks/CU on all 256 CUs, ticketed
//                     chunk-major 128x128 tiles; T=1024 tickets / 512 workers
//                     = exactly 2 each (no straggler round).
//   blocks 512..543 : scan blocks (one per batch), land as 3rd block on CUs
//                     0..31. 2 waves: wave0 = scan (LDS-fed, zero global
//                     loads in hot loop), wave1 = prefetcher (global->reg->
//                     LDS ring, chunk-gated, 2-stage pipelined).
// Shared memory is a union: GEMM staging (16.9KB) / scan ring 16 steps x 512
// floats + flags (32.8KB) -> block LDS 32.8KB, so GEMM keeps 2 blocks/CU and
// scan CUs hold 2 GEMM + 1 scan = 98KB.

#define ALPHA_F 0.95122942450071402f  // float(exp(-1/20))

constexpr int Bb = 32, T = 1024, D = 512, Hh = 512;
constexpr int M = Bb * T;              // 32768
constexpr int NGEMM = 512;             // 2 blocks/CU everywhere
constexpr int NTILES = (M / 128) * (Hh / 128);  // 1024
constexpr int RING = 16;               // LDS ring depth (timesteps)

#define BM 128
#define BN 128
#define BK 16
#define LDA (BM + 4)                   // padded leading dim (132)

// ------------------------------------------------------------ DPP reduce ----
template <int CTRL>
__device__ __forceinline__ float dpp_add(float v) {
  int s = __builtin_amdgcn_update_dpp(0, __builtin_bit_cast(int, v),
                                      CTRL, 0xF, 0xF, true);
  return v + __builtin_bit_cast(float, s);
}

// 64-lane sum; result valid in lane 63 only (caller readlanes).
__device__ __forceinline__ float dpp_reduce(float v) {
  v = dpp_add<0x111>(v);  // row_shr:1
  v = dpp_add<0x112>(v);  // row_shr:2
  v = dpp_add<0x114>(v);  // row_shr:4
  v = dpp_add<0x118>(v);  // row_shr:8
  v = dpp_add<0x142>(v);  // row_bcast15
  v = dpp_add<0x143>(v);  // row_bcast31 -> lane 63 = total
  return v;
}

// ------------------------------------------------------------- zero ws ----
__global__ void zero_ws_kernel(unsigned* ws) {
  if (threadIdx.x < 257) ws[threadIdx.x] = 0;  // prog[256] + ticket
}

// ------------------------------------------------------------ fused ----
__global__ __launch_bounds__(256) void fused_kernel(
    const float* __restrict__ X,     // [M, D]
    const float* __restrict__ W,     // [H, D]
    const float* __restrict__ bias,  // [H]
    const float* __restrict__ ta,    // [H]
    float* out,                      // [M, H]: xlin then spikes (in place)
    float* memout,                   // [B, H]
    unsigned* ws)                    // prog[256], ticket
{
  unsigned* prog = ws;
  unsigned* ticket = ws + 256;
  const int tid = threadIdx.x;

  // union: GEMM As/Bs (4224 floats) | scan ring (8192) + flags (2)
  __shared__ __align__(16) float sm[RING * 512 + 2];

#define RINGF(sl, h) sm[(sl) * 512 + (h)]

  if (blockIdx.x < NGEMM) {
    // ------------------------------ GEMM role (persistent, ticketed) ------
    __shared__ unsigned s_g;
    float* As = sm;                 // [BK][LDA]
    float* Bs = sm + BK * LDA;      // [BK][LDA]
    const int tm = tid >> 4;
    const int tn = tid & 15;
    for (;;) {
      __syncthreads();  // protects s_g WAR + As/Bs across tiles
      if (tid == 0)
        s_g = __hip_atomic_fetch_add(ticket, 1u, __ATOMIC_RELAXED,
                                     __HIP_MEMORY_SCOPE_AGENT);
      __syncthreads();
      const unsigned g = s_g;
      if (g >= NTILES) break;  // uniform
      // chunk-major decode: g = c*128 + bt*4 + bn ; bm = bt*8 + c
      const int c  = (int)(g >> 7);
      const int bt = (int)((g & 127u) >> 2);
      const int bn = (int)(g & 3u);
      const int bm = bt * 8 + c;
      const int rowA = bm * BM;
      const int rowB = bn * BN;

      float acc[8][8];
#pragma unroll
      for (int i = 0; i < 8; ++i)
#pragma unroll
        for (int j = 0; j < 8; ++j) acc[i][j] = 0.f;

      for (int k0 = 0; k0 < D; k0 += BK) {
        __syncthreads();
#pragma unroll
        for (int i = 0; i < 2; ++i) {
          const int f = tid * 2 + i;    // 0..511
          const int r = f >> 2;         // 0..127
          const int c4 = (f & 3) << 2;  // 0,4,8,12
          float4 a = *(const float4*)(X + (size_t)(rowA + r) * D + k0 + c4);
          As[(c4 + 0) * LDA + r] = a.x; As[(c4 + 1) * LDA + r] = a.y;
          As[(c4 + 2) * LDA + r] = a.z; As[(c4 + 3) * LDA + r] = a.w;
          float4 w = *(const float4*)(W + (size_t)(rowB + r) * D + k0 + c4);
          Bs[(c4 + 0) * LDA + r] = w.x; Bs[(c4 + 1) * LDA + r] = w.y;
          Bs[(c4 + 2) * LDA + r] = w.z; Bs[(c4 + 3) * LDA + r] = w.w;
        }
        __syncthreads();
#pragma unroll
        for (int k = 0; k < BK; ++k) {
          float4 a0 = *(const float4*)&As[k * LDA + tm * 4];
          float4 a1 = *(const float4*)&As[k * LDA + 64 + tm * 4];
          float4 b0 = *(const float4*)&Bs[k * LDA + tn * 4];
          float4 b1 = *(const float4*)&Bs[k * LDA + 64 + tn * 4];
          float av[8] = {a0.x, a0.y, a0.z, a0.w, a1.x, a1.y, a1.z, a1.w};
          float bv[8] = {b0.x, b0.y, b0.z, b0.w, b1.x, b1.y, b1.z, b1.w};
#pragma unroll
          for (int i = 0; i < 8; ++i)
#pragma unroll
            for (int j = 0; j < 8; ++j)
              acc[i][j] = fmaf(av[i], bv[j], acc[i][j]);
        }
      }

      const int c0 = rowB + tn * 4;
      const int c1 = rowB + 64 + tn * 4;
      float4 bb0 = *(const float4*)(bias + c0);
      float4 bb1 = *(const float4*)(bias + c1);
      float bc[8] = {bb0.x, bb0.y, bb0.z, bb0.w, bb1.x, bb1.y, bb1.z, bb1.w};
#pragma unroll
      for (int i = 0; i < 8; ++i) {
        const int r = rowA + ((i < 4) ? (tm * 4 + i) : (64 + tm * 4 + (i - 4)));
        float4 v0, v1;
        v0.x = acc[i][0] + bc[0]; v0.y = acc[i][1] + bc[1];
        v0.z = acc[i][2] + bc[2]; v0.w = acc[i][3] + bc[3];
        v1.x = acc[i][4] + bc[4]; v1.y = acc[i][5] + bc[5];
        v1.z = acc[i][6] + bc[6]; v1.w = acc[i][7] + bc[7];
        *(float4*)(out + (size_t)r * Hh + c0) = v0;
        *(float4*)(out + (size_t)r * Hh + c1) = v1;
      }
      __syncthreads();  // barrier drain: all waves' stores at vmcnt(0)
      if (tid == 0)
        __hip_atomic_fetch_add(prog + bm, 1u, __ATOMIC_RELEASE,
                               __HIP_MEMORY_SCOPE_AGENT);
    }
    return;
  }

  // ---------------------------------------------------------- scan role ----
  const int b = (int)blockIdx.x - NGEMM;  // 0..31
  unsigned* fillp = (unsigned*)&sm[RING * 512];
  unsigned* consp = fillp + 1;
  if (tid == 0) { *fillp = 0u; *consp = 0u; }
  __syncthreads();           // all 4 waves present; flags initialized
  if (tid >= 128) return;    // waves 2,3 exit

  const int wv = tid >> 6;   // 0 = scan, 1 = prefetcher
  const int lane = tid & 63;
  float* base = out + (size_t)b * (size_t)(T * Hh);

#define WAIT_CHUNK(idx)                                                      \
  {                                                                          \
    unsigned* wp = prog + (idx);                                             \
    while (__hip_atomic_load(wp, __ATOMIC_RELAXED,                           \
                             __HIP_MEMORY_SCOPE_AGENT) < 4u) {               \
      __builtin_amdgcn_s_sleep(2);                                           \
    }                                                                        \
    __builtin_amdgcn_fence(__ATOMIC_ACQUIRE, "agent");                       \
  }

  if (wv == 1) {
    // -------------------------------------------------- prefetcher wave ---
    __builtin_amdgcn_s_setprio(1);
    const int hp0 = lane * 4, hp1 = 256 + lane * 4;
    unsigned consseen = 0;
    float4 va[8], vb[8];

    WAIT_CHUNK(b * 8);  // chunk 0
#pragma unroll
    for (int u = 0; u < 4; ++u) {  // group 0 -> va
      va[2 * u]     = *(const float4*)(base + (size_t)u * Hh + hp0);
      va[2 * u + 1] = *(const float4*)(base + (size_t)u * Hh + hp1);
    }

    for (int g = 0; g < 256; g += 2) {
      // ---- load group g+1 into vb (tb always < T since g <= 254) ----
      {
        const int tb = (g + 1) * 4;
        if ((tb & 127) == 0) WAIT_CHUNK(b * 8 + (tb >> 7));
#pragma unroll
        for (int u = 0; u < 4; ++u) {
          vb[2 * u]     = *(const float4*)(base + (size_t)(tb + u) * Hh + hp0);
          vb[2 * u + 1] = *(const float4*)(base + (size_t)(tb + u) * Hh + hp1);
        }
      }
      // ---- write group g (va), publish ----
      {
        const unsigned fe = (unsigned)((g + 1) * 4);
        while (fe > consseen + (unsigned)RING) {
          __builtin_amdgcn_s_sleep(1);
          consseen = __hip_atomic_load(consp, __ATOMIC_RELAXED,
                                       __HIP_MEMORY_SCOPE_WORKGROUP);
        }
#pragma unroll
        for (int u = 0; u < 4; ++u) {
          const int sl = (g * 4 + u) & (RING - 1);
          *(float4*)&RINGF(sl, hp0) = va[2 * u];
          *(float4*)&RINGF(sl, hp1) = va[2 * u + 1];
        }
        __hip_atomic_store(fillp, fe, __ATOMIC_RELEASE,
                           __HIP_MEMORY_SCOPE_WORKGROUP);
      }
      // ---- load group g+2 into va (guard end) ----
      {
        const int tb = (g + 2) * 4;
        if (tb < T) {
          if ((tb & 127) == 0) WAIT_CHUNK(b * 8 + (tb >> 7));
#pragma unroll
          for (int u = 0; u < 4; ++u) {
            va[2 * u]     = *(const float4*)(base + (size_t)(tb + u) * Hh + hp0);
            va[2 * u + 1] = *(const float4*)(base + (size_t)(tb + u) * Hh + hp1);
          }
        }
      }
      // ---- write group g+1 (vb), publish ----
      {
        const unsigned fe = (unsigned)((g + 2) * 4);
        while (fe > consseen + (unsigned)RING) {
          __builtin_amdgcn_s_sleep(1);
          consseen = __hip_atomic_load(consp, __ATOMIC_RELAXED,
                                       __HIP_MEMORY_SCOPE_WORKGROUP);
        }
#pragma unroll
        for (int u = 0; u < 4; ++u) {
          const int sl = ((g + 1) * 4 + u) & (RING - 1);
          *(float4*)&RINGF(sl, hp0) = vb[2 * u];
          *(float4*)&RINGF(sl, hp1) = vb[2 * u + 1];
        }
        __hip_atomic_store(fillp, fe, __ATOMIC_RELEASE,
                           __HIP_MEMORY_SCOPE_WORKGROUP);
      }
    }
    return;
  }

  // ------------------------------------------------------- scan wave ------
  __builtin_amdgcn_s_setprio(3);
  const int h0 = lane * 4, h1 = 256 + lane * 4;

  float4 tav0 = *(const float4*)(ta + h0);
  float4 tav1 = *(const float4*)(ta + h1);
  float tac[8] = {tav0.x, tav0.y, tav0.z, tav0.w,
                  tav1.x, tav1.y, tav1.z, tav1.w};

  unsigned fillseen = 0;
  while (fillseen < 8u)
    fillseen = __hip_atomic_load(fillp, __ATOMIC_ACQUIRE,
                                 __HIP_MEMORY_SCOPE_WORKGROUP);

  float4 pa[4], pb[4];
#pragma unroll
  for (int u = 0; u < 4; ++u) {
    pa[u] = *(const float4*)&RINGF(u, h0);
    pb[u] = *(const float4*)&RINGF(u, h1);
  }

  float cc[8], mr[8];
  bool fire[8];
  cc[0] = pa[0].x; cc[1] = pa[0].y; cc[2] = pa[0].z; cc[3] = pa[0].w;
  cc[4] = pb[0].x; cc[5] = pb[0].y; cc[6] = pb[0].z; cc[7] = pb[0].w;
#pragma unroll
  for (int i = 0; i < 8; ++i) fire[i] = false;

  // One step; u = compile-time 0..3 within the group; t = t0 + u.
#define STEPL(u)                                                             \
  {                                                                          \
    constexpr int u4 = (u) & 3;                                              \
    constexpr int n4 = ((u) + 1) & 3;                                        \
    const int t = t0 + (u);                                                  \
    const float xu_[8] = {pa[u4].x, pa[u4].y, pa[u4].z, pa[u4].w,            \
                          pb[u4].x, pb[u4].y, pb[u4].z, pb[u4].w};           \
    _Pragma("unroll")                                                        \
    for (int i = 0; i < 8; ++i) mr[i] = fire[i] ? xu_[i] : cc[i];            \
    {                                                                        \
      const int tp = t + 4;                                                  \
      if (tp < T) { /* uniform */                                            \
        const int sl = tp & (RING - 1);                                      \
        pa[u4] = *(const float4*)&RINGF(sl, h0);                             \
        pb[u4] = *(const float4*)&RINGF(sl, h1);                             \
      }                                                                      \
    }                                                                        \
    float s_ = ((mr[0] + mr[1]) + (mr[2] + mr[3])) +                         \
               ((mr[4] + mr[5]) + (mr[6] + mr[7]));                          \
    float q_ = ((fmaf(mr[0], mr[0], mr[1] * mr[1])) +                        \
                (fmaf(mr[2], mr[2], mr[3] * mr[3]))) +                       \
               ((fmaf(mr[4], mr[4], mr[5] * mr[5])) +                        \
                (fmaf(mr[6], mr[6], mr[7] * mr[7])));                        \
    { /* speculative next step from pa[n4] */                                \
      const float xn_[8] = {pa[n4].x, pa[n4].y, pa[n4].z, pa[n4].w,          \
                            pb[n4].x, pb[n4].y, pb[n4].z, pb[n4].w};         \
      _Pragma("unroll")                                                      \
      for (int i = 0; i < 8; ++i) cc[i] = fmaf(ALPHA_F, mr[i], xn_[i]);      \
    }                                                                        \
    s_ = dpp_reduce(s_);                                                     \
    q_ = dpp_reduce(q_);                                                     \
    float var_ = fmaf(s_ * s_, -(1.0f / Hh), q_) * (1.0f / (Hh - 1));        \
    var_ = fmaxf(var_, 0.f);                                                 \
    float sdl_ = __builtin_amdgcn_sqrtf(var_); /* lane 63 valid */           \
    const float sd_ = __builtin_bit_cast(                                    \
        float,                                                               \
        __builtin_amdgcn_readlane(__builtin_bit_cast(int, sdl_), 63));       \
    float sp[8];                                                             \
    _Pragma("unroll")                                                        \
    for (int i = 0; i < 8; ++i) {                                            \
      fire[i] = mr[i] >= fmaf(0.1f, sd_, tac[i]);                            \
      sp[i] = fire[i] ? 1.f : 0.f;                                           \
    }                                                                        \
    *(float4*)(base + (size_t)t * Hh + h0) =                                 \
        make_float4(sp[0], sp[1], sp[2], sp[3]);                             \
    *(float4*)(base + (size_t)t * Hh + h1) =                                 \
        make_float4(sp[4], sp[5], sp[6], sp[7]);                             \
  }

  for (int gs = 0; gs < 256; ++gs) {
    unsigned need = (unsigned)((gs + 2) * 4);
    if (need > (unsigned)T) need = (unsigned)T;
    while (fillseen < need)
      fillseen = __hip_atomic_load(fillp, __ATOMIC_ACQUIRE,
                                   __HIP_MEMORY_SCOPE_WORKGROUP);
    const int t0 = gs * 4;
    STEPL(0)
    STEPL(1)
    STEPL(2)
    STEPL(3)
    __hip_atomic_store(consp, (unsigned)(t0 + 4), __ATOMIC_RELEASE,
                       __HIP_MEMORY_SCOPE_WORKGROUP);
  }
#undef STEPL
#undef WAIT_CHUNK

  float mf[8];
#pragma unroll
  for (int i = 0; i < 8; ++i) mf[i] = fire[i] ? 0.f : mr[i];
  *(float4*)(memout + (size_t)b * Hh + h0) = make_float4(mf[0], mf[1], mf[2], mf[3]);
  *(float4*)(memout + (size_t)b * Hh + h1) = make_float4(mf[4], mf[5], mf[6], mf[7]);
}

// ------------------------------------------------- fallback (R2 proven) ----
__global__ __launch_bounds__(256) void gemm_kernel(
    const float* __restrict__ X, const float* __restrict__ W,
    const float* __restrict__ bias, float* __restrict__ out) {
  const int bn = blockIdx.x, bm = blockIdx.y;
  __shared__ float As[BK][BM + 4];
  __shared__ float Bs[BK][BN + 4];
  const int tid = threadIdx.x, tm = tid >> 4, tn = tid & 15;
  float acc[8][8];
#pragma unroll
  for (int i = 0; i < 8; ++i)
#pragma unroll
    for (int j = 0; j < 8; ++j) acc[i][j] = 0.f;
  const int rowA = bm * BM, rowB = bn * BN;
  for (int k0 = 0; k0 < D; k0 += BK) {
    __syncthreads();
#pragma unroll
    for (int i = 0; i < 2; ++i) {
      const int f = tid * 2 + i, r = f >> 2, c4 = (f & 3) << 2;
      float4 a = *(const float4*)(X + (size_t)(rowA + r) * D + k0 + c4);
      As[c4 + 0][r] = a.x; As[c4 + 1][r] = a.y;
      As[c4 + 2][r] = a.z; As[c4 + 3][r] = a.w;
      float4 w = *(const float4*)(W + (size_t)(rowB + r) * D + k0 + c4);
      Bs[c4 + 0][r] = w.x; Bs[c4 + 1][r] = w.y;
      Bs[c4 + 2][r] = w.z; Bs[c4 + 3][r] = w.w;
    }
    __syncthreads();
#pragma unroll
    for (int k = 0; k < BK; ++k) {
      float4 a0 = *(const float4*)&As[k][tm * 4];
      float4 a1 = *(const float4*)&As[k][64 + tm * 4];
      float4 b0 = *(const float4*)&Bs[k][tn * 4];
      float4 b1 = *(const float4*)&Bs[k][64 + tn * 4];
      float av[8] = {a0.x, a0.y, a0.z, a0.w, a1.x, a1.y, a1.z, a1.w};
      float bv[8] = {b0.x, b0.y, b0.z, b0.w, b1.x, b1.y, b1.z, b1.w};
#pragma unroll
      for (int i = 0; i < 8; ++i)
#pragma unroll
        for (int j = 0; j < 8; ++j)
          acc[i][j] = fmaf(av[i], bv[j], acc[i][j]);
    }
  }
  const int c0 = rowB + tn * 4, c1 = rowB + 64 + tn * 4;
  float4 bb0 = *(const float4*)(bias + c0);
  float4 bb1 = *(const float4*)(bias + c1);
  float bc[8] = {bb0.x, bb0.y, bb0.z, bb0.w, bb1.x, bb1.y, bb1.z, bb1.w};
#pragma unroll
  for (int i = 0; i < 8; ++i) {
    const int r = rowA + ((i < 4) ? (tm * 4 + i) : (64 + tm * 4 + (i - 4)));
    float4 v0, v1;
    v0.x = acc[i][0] + bc[0]; v0.y = acc[i][1] + bc[1];
    v0.z = acc[i][2] + bc[2]; v0.w = acc[i][3] + bc[3];
    v1.x = acc[i][4] + bc[4]; v1.y = acc[i][5] + bc[5];
    v1.z = acc[i][6] + bc[6]; v1.w = acc[i][7] + bc[7];
    *(float4*)(out + (size_t)r * Hh + c0) = v0;
    *(float4*)(out + (size_t)r * Hh + c1) = v1;
  }
}

__global__ __launch_bounds__(64) void scan_kernel(
    float* __restrict__ xs, const float* __restrict__ ta,
    float* __restrict__ memout) {
  const int b = blockIdx.x, lane = threadIdx.x;
  float* base = xs + (size_t)b * (size_t)(T * Hh);
  const int h0 = lane * 4, h1 = 256 + lane * 4;
  float4 tav0 = *(const float4*)(ta + h0);
  float4 tav1 = *(const float4*)(ta + h1);
  float tac[8] = {tav0.x, tav0.y, tav0.z, tav0.w,
                  tav1.x, tav1.y, tav1.z, tav1.w};
  float4 pa[4], pb[4];
#pragma unroll
  for (int u = 0; u < 4; ++u) {
    pa[u] = *(const float4*)(base + (size_t)u * Hh + h0);
    pb[u] = *(const float4*)(base + (size_t)u * Hh + h1);
  }
  float xc[8], cc[8], mr[8];
  bool fire[8];
  {
    const float4 a = pa[0], bq = pb[0];
    xc[0] = a.x; xc[1] = a.y; xc[2] = a.z; xc[3] = a.w;
    xc[4] = bq.x; xc[5] = bq.y; xc[6] = bq.z; xc[7] = bq.w;
  }
#pragma unroll
  for (int i = 0; i < 8; ++i) { cc[i] = xc[i]; fire[i] = false; }
  for (int t = 0; t < T; ++t) {
    const int u = t & 3;
    if (t + 4 < T) {
      pa[u] = *(const float4*)(base + (size_t)(t + 4) * Hh + h0);
      pb[u] = *(const float4*)(base + (size_t)(t + 4) * Hh + h1);
    }
#pragma unroll
    for (int i = 0; i < 8; ++i) mr[i] = fire[i] ? xc[i] : cc[i];
    float s = ((mr[0] + mr[1]) + (mr[2] + mr[3])) +
              ((mr[4] + mr[5]) + (mr[6] + mr[7]));
    float q = ((mr[0] * mr[0] + mr[1] * mr[1]) +
               (mr[2] * mr[2] + mr[3] * mr[3])) +
              ((mr[4] * mr[4] + mr[5] * mr[5]) +
               (mr[6] * mr[6] + mr[7] * mr[7]));
    {
      const float4 na = pa[(u + 1) & 3];
      const float4 nb = pb[(u + 1) & 3];
      xc[0] = na.x; xc[1] = na.y; xc[2] = na.z; xc[3] = na.w;
      xc[4] = nb.x; xc[5] = nb.y; xc[6] = nb.z; xc[7] = nb.w;
#pragma unroll
      for (int i = 0; i < 8; ++i) cc[i] = fmaf(ALPHA_F, mr[i], xc[i]);
    }
    s = dpp_reduce(s);
    q = dpp_reduce(q);
    float var = fmaxf((q - s * s * (1.0f / Hh)) * (1.0f / (Hh - 1)), 0.f);
    float sdl = __builtin_amdgcn_sqrtf(var);
    const float sd = __builtin_bit_cast(
        float, __builtin_amdgcn_readlane(__builtin_bit_cast(int, sdl), 63));
    float sp[8];
#pragma unroll
    for (int i = 0; i < 8; ++i) {
      fire[i] = mr[i] >= fmaf(0.1f, sd, tac[i]);
      sp[i] = fire[i] ? 1.f : 0.f;
    }
    *(float4*)(base + (size_t)t * Hh + h0) = make_float4(sp[0], sp[1], sp[2], sp[3]);
    *(float4*)(base + (size_t)t * Hh + h1) = make_float4(sp[4], sp[5], sp[6], sp[7]);
  }
  float mf[8];
#pragma unroll
  for (int i = 0; i < 8; ++i) mf[i] = fire[i] ? 0.f : mr[i];
  *(float4*)(memout + (size_t)b * Hh + h0) = make_float4(mf[0], mf[1], mf[2], mf[3]);
  *(float4*)(memout + (size_t)b * Hh + h1) = make_float4(mf[4], mf[5], mf[6], mf[7]);
}

// -------------------------------------------------------------- launch ----
extern "C" void kernel_launch(void* const* d_in, const int* in_sizes, int n_in,
                              void* d_out, int out_size, void* d_ws,
                              size_t ws_size, hipStream_t stream) {
  const float* x    = (const float*)d_in[0];
  const float* W    = (const float*)d_in[1];
  const float* bias = (const float*)d_in[2];
  const float* ta   = (const float*)d_in[3];

  float* out    = (float*)d_out;
  float* spikes = out;
  float* memout = out + (size_t)Bb * T * Hh;

  if (ws_size >= 257 * sizeof(unsigned)) {
    unsigned* ws = (unsigned*)d_ws;
    zero_ws_kernel<<<dim3(1), dim3(512), 0, stream>>>(ws);
    fused_kernel<<<dim3(NGEMM + Bb), dim3(256), 0, stream>>>(
        x, W, bias, ta, spikes, memout, ws);
  } else {
    dim3 ggrid(Hh / BN, M / BM);
    gemm_kernel<<<ggrid, dim3(256), 0, stream>>>(x, W, bias, spikes);
    scan_kernel<<<dim3(Bb), dim3(64), 0, stream>>>(spikes, ta, memout);
  }
}

// Round 6
// 345.995 us; speedup vs baseline: 1.2005x; 1.2005x over previous
//
#include <hip/hip_runtime.h>

// SpikingNeuronLayer fused producer/consumer, R6:
//   grid = 256 blocks x 512 threads -> 1 block/CU (round-robin placement).
//   blocks 0..31   : scan role. Wave 0 scans batch b (register-resident
//                    prefetch ring, compile-time indexing -- R2's scratch bug
//                    fixed); waves 1..7 exit. Scan CU is otherwise idle.
//   blocks 32..255 : GEMM workers, 8 waves/CU (full CU), ticketed 128x256
//                    tiles in ch-major order so chunk ch of every batch lands
//                    in cadence; signal prog[mt] with agent-scope RELEASE.
// xlin lands in d_out's spike region and is overwritten in place by the scan.

#define ALPHA_F 0.95122942450071402f  // float(exp(-1/20))

constexpr int Bb = 32, T = 1024, D = 512, Hh = 512;
constexpr int M = Bb * T;              // 32768
constexpr int NSCAN = 32;
constexpr int NBLOCKS = 256;           // 32 scan + 224 GEMM workers
constexpr int NTILES = 512;            // (M/128) * (H/256)

#define BM 128
#define BN 256
#define BK 16
#define LDA (BM + 4)                   // 132
#define LDB (BN + 4)                   // 260

// ------------------------------------------------------------ DPP reduce ----
template <int CTRL>
__device__ __forceinline__ float dpp_add(float v) {
  int s = __builtin_amdgcn_update_dpp(0, __builtin_bit_cast(int, v),
                                      CTRL, 0xF, 0xF, true);
  return v + __builtin_bit_cast(float, s);
}

// 64-lane sum; result valid in lane 63 only (caller readlanes).
__device__ __forceinline__ float dpp_reduce(float v) {
  v = dpp_add<0x111>(v);  // row_shr:1
  v = dpp_add<0x112>(v);  // row_shr:2
  v = dpp_add<0x114>(v);  // row_shr:4
  v = dpp_add<0x118>(v);  // row_shr:8
  v = dpp_add<0x142>(v);  // row_bcast15
  v = dpp_add<0x143>(v);  // row_bcast31 -> lane 63 = total
  return v;
}

// ------------------------------------------------------------- zero ws ----
__global__ void zero_ws_kernel(unsigned* ws) {
  if (threadIdx.x < 257) ws[threadIdx.x] = 0;  // prog[256] + ticket
}

// ------------------------------------------------------------ fused ----
__global__ __launch_bounds__(512) void fused_kernel(
    const float* __restrict__ X,     // [M, D]
    const float* __restrict__ W,     // [H, D]
    const float* __restrict__ bias,  // [H]
    const float* __restrict__ ta,    // [H]
    float* out,                      // [M, H]: xlin then spikes (in place)
    float* memout,                   // [B, H]
    unsigned* ws)                    // prog[256] (per-mt), ticket
{
  unsigned* prog = ws;
  unsigned* ticket = ws + 256;
  const int tid = threadIdx.x;

  if (blockIdx.x >= NSCAN) {
    // ------------------------------ GEMM role (persistent, ticketed) ------
    __shared__ float As[BK][LDA];
    __shared__ float Bs[BK][LDB];
    __shared__ unsigned s_g;
    const int tm = tid >> 5;   // 0..15
    const int tn = tid & 31;   // 0..31
    for (;;) {
      __syncthreads();  // protects s_g WAR + As/Bs across tiles
      if (tid == 0)
        s_g = __hip_atomic_fetch_add(ticket, 1u, __ATOMIC_RELAXED,
                                     __HIP_MEMORY_SCOPE_AGENT);
      __syncthreads();
      const unsigned g = s_g;
      if (g >= NTILES) break;  // uniform
      // ch-major decode: g = ch*64 + idx ; mt = (idx>>1)*8 + ch ; bn = idx&1
      const int chg = (int)(g >> 6);          // 0..7 (time-chunk class)
      const int idx = (int)(g & 63u);
      const int mt  = (idx >> 1) * 8 + chg;   // 0..255 (128-row band)
      const int bn  = idx & 1;
      const int rowA = mt * BM;
      const int rowB = bn * BN;

      float acc[8][8];
#pragma unroll
      for (int i = 0; i < 8; ++i)
#pragma unroll
        for (int j = 0; j < 8; ++j) acc[i][j] = 0.f;

      for (int k0 = 0; k0 < D; k0 += BK) {
        __syncthreads();
        {  // A: 128 rows x 16 k = 512 float4, one per thread
          const int r = tid >> 2;             // 0..127
          const int c4 = (tid & 3) << 2;      // 0,4,8,12
          float4 a = *(const float4*)(X + (size_t)(rowA + r) * D + k0 + c4);
          As[c4 + 0][r] = a.x; As[c4 + 1][r] = a.y;
          As[c4 + 2][r] = a.z; As[c4 + 3][r] = a.w;
        }
#pragma unroll
        for (int i = 0; i < 2; ++i) {  // B: 256 rows x 16 k = 1024 float4
          const int f = tid + i * 512;
          const int r = f >> 2;               // 0..255
          const int c4 = (f & 3) << 2;
          float4 w = *(const float4*)(W + (size_t)(rowB + r) * D + k0 + c4);
          Bs[c4 + 0][r] = w.x; Bs[c4 + 1][r] = w.y;
          Bs[c4 + 2][r] = w.z; Bs[c4 + 3][r] = w.w;
        }
        __syncthreads();
#pragma unroll
        for (int k = 0; k < BK; ++k) {
          float4 a0 = *(const float4*)&As[k][tm * 4];
          float4 a1 = *(const float4*)&As[k][64 + tm * 4];
          float4 b0 = *(const float4*)&Bs[k][tn * 4];
          float4 b1 = *(const float4*)&Bs[k][128 + tn * 4];
          float av[8] = {a0.x, a0.y, a0.z, a0.w, a1.x, a1.y, a1.z, a1.w};
          float bv[8] = {b0.x, b0.y, b0.z, b0.w, b1.x, b1.y, b1.z, b1.w};
#pragma unroll
          for (int i = 0; i < 8; ++i)
#pragma unroll
            for (int j = 0; j < 8; ++j)
              acc[i][j] = fmaf(av[i], bv[j], acc[i][j]);
        }
      }

      const int c0 = rowB + tn * 4;
      const int c1 = rowB + 128 + tn * 4;
      float4 bb0 = *(const float4*)(bias + c0);
      float4 bb1 = *(const float4*)(bias + c1);
      float bc[8] = {bb0.x, bb0.y, bb0.z, bb0.w, bb1.x, bb1.y, bb1.z, bb1.w};
#pragma unroll
      for (int i = 0; i < 8; ++i) {
        const int r = rowA + ((i < 4) ? (tm * 4 + i) : (64 + tm * 4 + (i - 4)));
        float4 v0, v1;
        v0.x = acc[i][0] + bc[0]; v0.y = acc[i][1] + bc[1];
        v0.z = acc[i][2] + bc[2]; v0.w = acc[i][3] + bc[3];
        v1.x = acc[i][4] + bc[4]; v1.y = acc[i][5] + bc[5];
        v1.z = acc[i][6] + bc[6]; v1.w = acc[i][7] + bc[7];
        *(float4*)(out + (size_t)r * Hh + c0) = v0;
        *(float4*)(out + (size_t)r * Hh + c1) = v1;
      }
      __syncthreads();  // barrier drain: all waves' stores at vmcnt(0)
      if (tid == 0)
        __hip_atomic_fetch_add(prog + mt, 1u, __ATOMIC_RELEASE,
                               __HIP_MEMORY_SCOPE_AGENT);
    }
    return;
  }

  // ---------------------------------------------------------- scan role ----
  if (tid >= 64) return;  // one wave; rest of the block exits, CU stays clean
  __builtin_amdgcn_s_setprio(3);

  const int b = blockIdx.x;
  const int lane = tid;
  float* base = out + (size_t)b * (size_t)(T * Hh);
  const int h0 = lane * 4;
  const int h1 = 256 + lane * 4;

  float4 tav0 = *(const float4*)(ta + h0);
  float4 tav1 = *(const float4*)(ta + h1);
  float tac[8] = {tav0.x, tav0.y, tav0.z, tav0.w,
                  tav1.x, tav1.y, tav1.z, tav1.w};

  // chunk (b,ch) ready when prog[b*8+ch] == 2 (bn = 0,1 tiles done)
#define WAIT_CHUNK(idxc)                                                     \
  {                                                                          \
    unsigned* wp = prog + (idxc);                                            \
    while (__hip_atomic_load(wp, __ATOMIC_RELAXED,                           \
                             __HIP_MEMORY_SCOPE_AGENT) < 2u) {               \
      __builtin_amdgcn_s_sleep(2);                                           \
    }                                                                        \
    __builtin_amdgcn_fence(__ATOMIC_ACQUIRE, "agent");                       \
  }

  WAIT_CHUNK(b * 8);

  // prefetch depth 8: slot u holds timestep congruent to u (mod 8);
  // ALL indexing compile-time (macro-unrolled) -> stays in VGPRs.
  float4 pa[8], pb[8];
#pragma unroll
  for (int u = 0; u < 8; ++u) {
    pa[u] = *(const float4*)(base + (size_t)u * Hh + h0);
    pb[u] = *(const float4*)(base + (size_t)u * Hh + h1);
  }

  float cc[8], mr[8];
  bool fire[8];
#pragma unroll
  for (int i = 0; i < 8; ++i) fire[i] = false;
  cc[0] = pa[0].x; cc[1] = pa[0].y; cc[2] = pa[0].z; cc[3] = pa[0].w;
  cc[4] = pb[0].x; cc[5] = pb[0].y; cc[6] = pb[0].z; cc[7] = pb[0].w;

#define STEP(t, u, PF)                                                       \
  {                                                                          \
    constexpr int n_ = ((u) + 1) & 7;                                        \
    const float xu_[8] = {pa[u].x, pa[u].y, pa[u].z, pa[u].w,                \
                          pb[u].x, pb[u].y, pb[u].z, pb[u].w};               \
    _Pragma("unroll")                                                        \
    for (int i = 0; i < 8; ++i) mr[i] = fire[i] ? xu_[i] : cc[i];            \
    if (PF) {                                                                \
      pa[u] = *(const float4*)(base + (size_t)((t) + 8) * Hh + h0);          \
      pb[u] = *(const float4*)(base + (size_t)((t) + 8) * Hh + h1);          \
    }                                                                        \
    float s_ = ((mr[0] + mr[1]) + (mr[2] + mr[3])) +                         \
               ((mr[4] + mr[5]) + (mr[6] + mr[7]));                          \
    float q_ = ((fmaf(mr[0], mr[0], mr[1] * mr[1])) +                        \
                (fmaf(mr[2], mr[2], mr[3] * mr[3]))) +                       \
               ((fmaf(mr[4], mr[4], mr[5] * mr[5])) +                        \
                (fmaf(mr[6], mr[6], mr[7] * mr[7])));                        \
    { /* speculative next step from slot n_ (loaded t-7, intact) */          \
      const float xn_[8] = {pa[n_].x, pa[n_].y, pa[n_].z, pa[n_].w,          \
                            pb[n_].x, pb[n_].y, pb[n_].z, pb[n_].w};         \
      _Pragma("unroll")                                                      \
      for (int i = 0; i < 8; ++i) cc[i] = fmaf(ALPHA_F, mr[i], xn_[i]);      \
    }                                                                        \
    s_ = dpp_reduce(s_);                                                     \
    q_ = dpp_reduce(q_);                                                     \
    float var_ = fmaf(s_ * s_, -(1.0f / Hh), q_) * (1.0f / (Hh - 1));        \
    var_ = fmaxf(var_, 0.f);                                                 \
    float sdl_ = __builtin_amdgcn_sqrtf(var_); /* lane 63 valid */           \
    const float sd_ = __builtin_bit_cast(                                    \
        float,                                                               \
        __builtin_amdgcn_readlane(__builtin_bit_cast(int, sdl_), 63));       \
    float sp[8];                                                             \
    _Pragma("unroll")                                                        \
    for (int i = 0; i < 8; ++i) {                                            \
      fire[i] = mr[i] >= fmaf(0.1f, sd_, tac[i]);                            \
      sp[i] = fire[i] ? 1.f : 0.f;                                           \
    }                                                                        \
    *(float4*)(base + (size_t)(t) * Hh + h0) =                               \
        make_float4(sp[0], sp[1], sp[2], sp[3]);                             \
    *(float4*)(base + (size_t)(t) * Hh + h1) =                               \
        make_float4(sp[4], sp[5], sp[6], sp[7]);                             \
  }

#define STEP8(tb, PF)                                                        \
  STEP((tb) + 0, 0, PF) STEP((tb) + 1, 1, PF) STEP((tb) + 2, 2, PF)          \
  STEP((tb) + 3, 3, PF) STEP((tb) + 4, 4, PF) STEP((tb) + 5, 5, PF)          \
  STEP((tb) + 6, 6, PF) STEP((tb) + 7, 7, PF)

  for (int ch = 0; ch < 8; ++ch) {
    const int cb = ch << 7;
    for (int it = 0; it < 15; ++it) {  // steps cb..cb+119: prefetch in-chunk
      STEP8(cb + (it << 3), true)
    }
    // last 8 steps of chunk: prefetch crosses into chunk+1
    if (ch < 7) {
      WAIT_CHUNK(b * 8 + ch + 1);
      STEP8(cb + 120, true)
    } else {
      STEP8(cb + 120, false)
    }
  }
#undef STEP8
#undef STEP
#undef WAIT_CHUNK

  float mf[8];
#pragma unroll
  for (int i = 0; i < 8; ++i) mf[i] = fire[i] ? 0.f : mr[i];
  *(float4*)(memout + (size_t)b * Hh + h0) = make_float4(mf[0], mf[1], mf[2], mf[3]);
  *(float4*)(memout + (size_t)b * Hh + h1) = make_float4(mf[4], mf[5], mf[6], mf[7]);
}

// ------------------------------------------------- fallback (two-kernel) ----
__global__ __launch_bounds__(256) void gemm_kernel(
    const float* __restrict__ X, const float* __restrict__ W,
    const float* __restrict__ bias, float* __restrict__ out) {
  const int bn = blockIdx.x, bm = blockIdx.y;
  __shared__ float As[BK][BM + 4];
  __shared__ float Bs[BK][BM + 4];
  const int tid = threadIdx.x, tm = tid >> 4, tn = tid & 15;
  float acc[8][8];
#pragma unroll
  for (int i = 0; i < 8; ++i)
#pragma unroll
    for (int j = 0; j < 8; ++j) acc[i][j] = 0.f;
  const int rowA = bm * BM, rowB = bn * BM;
  for (int k0 = 0; k0 < D; k0 += BK) {
    __syncthreads();
#pragma unroll
    for (int i = 0; i < 2; ++i) {
      const int f = tid * 2 + i, r = f >> 2, c4 = (f & 3) << 2;
      float4 a = *(const float4*)(X + (size_t)(rowA + r) * D + k0 + c4);
      As[c4 + 0][r] = a.x; As[c4 + 1][r] = a.y;
      As[c4 + 2][r] = a.z; As[c4 + 3][r] = a.w;
      float4 w = *(const float4*)(W + (size_t)(rowB + r) * D + k0 + c4);
      Bs[c4 + 0][r] = w.x; Bs[c4 + 1][r] = w.y;
      Bs[c4 + 2][r] = w.z; Bs[c4 + 3][r] = w.w;
    }
    __syncthreads();
#pragma unroll
    for (int k = 0; k < BK; ++k) {
      float4 a0 = *(const float4*)&As[k][tm * 4];
      float4 a1 = *(const float4*)&As[k][64 + tm * 4];
      float4 b0 = *(const float4*)&Bs[k][tn * 4];
      float4 b1 = *(const float4*)&Bs[k][64 + tn * 4];
      float av[8] = {a0.x, a0.y, a0.z, a0.w, a1.x, a1.y, a1.z, a1.w};
      float bv[8] = {b0.x, b0.y, b0.z, b0.w, b1.x, b1.y, b1.z, b1.w};
#pragma unroll
      for (int i = 0; i < 8; ++i)
#pragma unroll
        for (int j = 0; j < 8; ++j)
          acc[i][j] = fmaf(av[i], bv[j], acc[i][j]);
    }
  }
  const int c0 = rowB + tn * 4, c1 = rowB + 64 + tn * 4;
  float4 bb0 = *(const float4*)(bias + c0);
  float4 bb1 = *(const float4*)(bias + c1);
  float bc[8] = {bb0.x, bb0.y, bb0.z, bb0.w, bb1.x, bb1.y, bb1.z, bb1.w};
#pragma unroll
  for (int i = 0; i < 8; ++i) {
    const int r = rowA + ((i < 4) ? (tm * 4 + i) : (64 + tm * 4 + (i - 4)));
    float4 v0, v1;
    v0.x = acc[i][0] + bc[0]; v0.y = acc[i][1] + bc[1];
    v0.z = acc[i][2] + bc[2]; v0.w = acc[i][3] + bc[3];
    v1.x = acc[i][4] + bc[4]; v1.y = acc[i][5] + bc[5];
    v1.z = acc[i][6] + bc[6]; v1.w = acc[i][7] + bc[7];
    *(float4*)(out + (size_t)r * Hh + c0) = v0;
    *(float4*)(out + (size_t)r * Hh + c1) = v1;
  }
}

__global__ __launch_bounds__(64) void scan_kernel(
    float* __restrict__ xs, const float* __restrict__ ta,
    float* __restrict__ memout) {
  const int b = blockIdx.x, lane = threadIdx.x;
  float* base = xs + (size_t)b * (size_t)(T * Hh);
  const int h0 = lane * 4, h1 = 256 + lane * 4;
  float4 tav0 = *(const float4*)(ta + h0);
  float4 tav1 = *(const float4*)(ta + h1);
  float tac[8] = {tav0.x, tav0.y, tav0.z, tav0.w,
                  tav1.x, tav1.y, tav1.z, tav1.w};
  float4 pa[4], pb[4];
#pragma unroll
  for (int u = 0; u < 4; ++u) {
    pa[u] = *(const float4*)(base + (size_t)u * Hh + h0);
    pb[u] = *(const float4*)(base + (size_t)u * Hh + h1);
  }
  float xc[8], cc[8], mr[8];
  bool fire[8];
  {
    const float4 a = pa[0], bq = pb[0];
    xc[0] = a.x; xc[1] = a.y; xc[2] = a.z; xc[3] = a.w;
    xc[4] = bq.x; xc[5] = bq.y; xc[6] = bq.z; xc[7] = bq.w;
  }
#pragma unroll
  for (int i = 0; i < 8; ++i) { cc[i] = xc[i]; fire[i] = false; }
#pragma unroll 4
  for (int t = 0; t < T; ++t) {
    const int u = t & 3;
    if (t + 4 < T) {
      pa[u] = *(const float4*)(base + (size_t)(t + 4) * Hh + h0);
      pb[u] = *(const float4*)(base + (size_t)(t + 4) * Hh + h1);
    }
#pragma unroll
    for (int i = 0; i < 8; ++i) mr[i] = fire[i] ? xc[i] : cc[i];
    float s = ((mr[0] + mr[1]) + (mr[2] + mr[3])) +
              ((mr[4] + mr[5]) + (mr[6] + mr[7]));
    float q = ((mr[0] * mr[0] + mr[1] * mr[1]) +
               (mr[2] * mr[2] + mr[3] * mr[3])) +
              ((mr[4] * mr[4] + mr[5] * mr[5]) +
               (mr[6] * mr[6] + mr[7] * mr[7]));
    {
      const float4 na = pa[(u + 1) & 3];
      const float4 nb = pb[(u + 1) & 3];
      xc[0] = na.x; xc[1] = na.y; xc[2] = na.z; xc[3] = na.w;
      xc[4] = nb.x; xc[5] = nb.y; xc[6] = nb.z; xc[7] = nb.w;
#pragma unroll
      for (int i = 0; i < 8; ++i) cc[i] = fmaf(ALPHA_F, mr[i], xc[i]);
    }
    s = dpp_reduce(s);
    q = dpp_reduce(q);
    float var = fmaxf((q - s * s * (1.0f / Hh)) * (1.0f / (Hh - 1)), 0.f);
    float sdl = __builtin_amdgcn_sqrtf(var);
    const float sd = __builtin_bit_cast(
        float, __builtin_amdgcn_readlane(__builtin_bit_cast(int, sdl), 63));
    float sp[8];
#pragma unroll
    for (int i = 0; i < 8; ++i) {
      fire[i] = mr[i] >= fmaf(0.1f, sd, tac[i]);
      sp[i] = fire[i] ? 1.f : 0.f;
    }
    *(float4*)(base + (size_t)t * Hh + h0) = make_float4(sp[0], sp[1], sp[2], sp[3]);
    *(float4*)(base + (size_t)t * Hh + h1) = make_float4(sp[4], sp[5], sp[6], sp[7]);
  }
  float mf[8];
#pragma unroll
  for (int i = 0; i < 8; ++i) mf[i] = fire[i] ? 0.f : mr[i];
  *(float4*)(memout + (size_t)b * Hh + h0) = make_float4(mf[0], mf[1], mf[2], mf[3]);
  *(float4*)(memout + (size_t)b * Hh + h1) = make_float4(mf[4], mf[5], mf[6], mf[7]);
}

// -------------------------------------------------------------- launch ----
extern "C" void kernel_launch(void* const* d_in, const int* in_sizes, int n_in,
                              void* d_out, int out_size, void* d_ws,
                              size_t ws_size, hipStream_t stream) {
  const float* x    = (const float*)d_in[0];
  const float* W    = (const float*)d_in[1];
  const float* bias = (const float*)d_in[2];
  const float* ta   = (const float*)d_in[3];

  float* out    = (float*)d_out;
  float* spikes = out;
  float* memout = out + (size_t)Bb * T * Hh;

  if (ws_size >= 257 * sizeof(unsigned)) {
    unsigned* ws = (unsigned*)d_ws;
    zero_ws_kernel<<<dim3(1), dim3(512), 0, stream>>>(ws);
    fused_kernel<<<dim3(NBLOCKS), dim3(512), 0, stream>>>(
        x, W, bias, ta, spikes, memout, ws);
  } else {
    dim3 ggrid(Hh / 128, M / BM);
    gemm_kernel<<<ggrid, dim3(256), 0, stream>>>(x, W, bias, spikes);
    scan_kernel<<<dim3(Bb), dim3(64), 0, stream>>>(spikes, ta, memout);
  }
}

// Round 7
// 324.786 us; speedup vs baseline: 1.2788x; 1.0653x over previous
//
#include <hip/hip_runtime.h>

// SpikingNeuronLayer fused producer/consumer, R7:
//   grid = 256 blocks x 512 threads -> 1 block/CU (round-robin placement).
//   blocks 0..31   : scan role, wave 0 only. R7: batch double-buffered
//                    prefetch -- 8-step groups, issue 16 loads for the NEXT
//                    group up front (into the alternate register buffer, all
//                    compile-time indices), then 8 steps of pure-VALU compute.
//                    One vmcnt wait per group (~2 groups of latency cover).
//   blocks 32..255 : GEMM workers (identical to R6), ticketed 128x256 tiles,
//                    ch-major order, signal prog[mt] with agent RELEASE.
// xlin lands in d_out's spike region and is overwritten in place by the scan.

#define ALPHA_F 0.95122942450071402f  // float(exp(-1/20))

constexpr int Bb = 32, T = 1024, D = 512, Hh = 512;
constexpr int M = Bb * T;              // 32768
constexpr int NSCAN = 32;
constexpr int NBLOCKS = 256;           // 32 scan + 224 GEMM workers
constexpr int NTILES = 512;            // (M/128) * (H/256)

#define BM 128
#define BN 256
#define BK 16
#define LDA (BM + 4)                   // 132
#define LDB (BN + 4)                   // 260

// ------------------------------------------------------------ DPP reduce ----
template <int CTRL>
__device__ __forceinline__ float dpp_add(float v) {
  int s = __builtin_amdgcn_update_dpp(0, __builtin_bit_cast(int, v),
                                      CTRL, 0xF, 0xF, true);
  return v + __builtin_bit_cast(float, s);
}

// 64-lane sum; result valid in lane 63 only (caller readlanes).
__device__ __forceinline__ float dpp_reduce(float v) {
  v = dpp_add<0x111>(v);  // row_shr:1
  v = dpp_add<0x112>(v);  // row_shr:2
  v = dpp_add<0x114>(v);  // row_shr:4
  v = dpp_add<0x118>(v);  // row_shr:8
  v = dpp_add<0x142>(v);  // row_bcast15
  v = dpp_add<0x143>(v);  // row_bcast31 -> lane 63 = total
  return v;
}

// ------------------------------------------------------------- zero ws ----
__global__ void zero_ws_kernel(unsigned* ws) {
  if (threadIdx.x < 257) ws[threadIdx.x] = 0;  // prog[256] + ticket
}

// ------------------------------------------------------------ fused ----
__global__ __launch_bounds__(512) void fused_kernel(
    const float* __restrict__ X,     // [M, D]
    const float* __restrict__ W,     // [H, D]
    const float* __restrict__ bias,  // [H]
    const float* __restrict__ ta,    // [H]
    float* out,                      // [M, H]: xlin then spikes (in place)
    float* memout,                   // [B, H]
    unsigned* ws)                    // prog[256] (per-mt), ticket
{
  unsigned* prog = ws;
  unsigned* ticket = ws + 256;
  const int tid = threadIdx.x;

  if (blockIdx.x >= NSCAN) {
    // ------------------------------ GEMM role (persistent, ticketed) ------
    __shared__ float As[BK][LDA];
    __shared__ float Bs[BK][LDB];
    __shared__ unsigned s_g;
    const int tm = tid >> 5;   // 0..15
    const int tn = tid & 31;   // 0..31
    for (;;) {
      __syncthreads();  // protects s_g WAR + As/Bs across tiles
      if (tid == 0)
        s_g = __hip_atomic_fetch_add(ticket, 1u, __ATOMIC_RELAXED,
                                     __HIP_MEMORY_SCOPE_AGENT);
      __syncthreads();
      const unsigned g = s_g;
      if (g >= NTILES) break;  // uniform
      // ch-major decode: g = ch*64 + idx ; mt = (idx>>1)*8 + ch ; bn = idx&1
      const int chg = (int)(g >> 6);          // 0..7 (time-chunk class)
      const int idx = (int)(g & 63u);
      const int mt  = (idx >> 1) * 8 + chg;   // 0..255 (128-row band)
      const int bn  = idx & 1;
      const int rowA = mt * BM;
      const int rowB = bn * BN;

      float acc[8][8];
#pragma unroll
      for (int i = 0; i < 8; ++i)
#pragma unroll
        for (int j = 0; j < 8; ++j) acc[i][j] = 0.f;

      for (int k0 = 0; k0 < D; k0 += BK) {
        __syncthreads();
        {  // A: 128 rows x 16 k = 512 float4, one per thread
          const int r = tid >> 2;             // 0..127
          const int c4 = (tid & 3) << 2;      // 0,4,8,12
          float4 a = *(const float4*)(X + (size_t)(rowA + r) * D + k0 + c4);
          As[c4 + 0][r] = a.x; As[c4 + 1][r] = a.y;
          As[c4 + 2][r] = a.z; As[c4 + 3][r] = a.w;
        }
#pragma unroll
        for (int i = 0; i < 2; ++i) {  // B: 256 rows x 16 k = 1024 float4
          const int f = tid + i * 512;
          const int r = f >> 2;               // 0..255
          const int c4 = (f & 3) << 2;
          float4 w = *(const float4*)(W + (size_t)(rowB + r) * D + k0 + c4);
          Bs[c4 + 0][r] = w.x; Bs[c4 + 1][r] = w.y;
          Bs[c4 + 2][r] = w.z; Bs[c4 + 3][r] = w.w;
        }
        __syncthreads();
#pragma unroll
        for (int k = 0; k < BK; ++k) {
          float4 a0 = *(const float4*)&As[k][tm * 4];
          float4 a1 = *(const float4*)&As[k][64 + tm * 4];
          float4 b0 = *(const float4*)&Bs[k][tn * 4];
          float4 b1 = *(const float4*)&Bs[k][128 + tn * 4];
          float av[8] = {a0.x, a0.y, a0.z, a0.w, a1.x, a1.y, a1.z, a1.w};
          float bv[8] = {b0.x, b0.y, b0.z, b0.w, b1.x, b1.y, b1.z, b1.w};
#pragma unroll
          for (int i = 0; i < 8; ++i)
#pragma unroll
            for (int j = 0; j < 8; ++j)
              acc[i][j] = fmaf(av[i], bv[j], acc[i][j]);
        }
      }

      const int c0 = rowB + tn * 4;
      const int c1 = rowB + 128 + tn * 4;
      float4 bb0 = *(const float4*)(bias + c0);
      float4 bb1 = *(const float4*)(bias + c1);
      float bc[8] = {bb0.x, bb0.y, bb0.z, bb0.w, bb1.x, bb1.y, bb1.z, bb1.w};
#pragma unroll
      for (int i = 0; i < 8; ++i) {
        const int r = rowA + ((i < 4) ? (tm * 4 + i) : (64 + tm * 4 + (i - 4)));
        float4 v0, v1;
        v0.x = acc[i][0] + bc[0]; v0.y = acc[i][1] + bc[1];
        v0.z = acc[i][2] + bc[2]; v0.w = acc[i][3] + bc[3];
        v1.x = acc[i][4] + bc[4]; v1.y = acc[i][5] + bc[5];
        v1.z = acc[i][6] + bc[6]; v1.w = acc[i][7] + bc[7];
        *(float4*)(out + (size_t)r * Hh + c0) = v0;
        *(float4*)(out + (size_t)r * Hh + c1) = v1;
      }
      __syncthreads();  // barrier drain: all waves' stores at vmcnt(0)
      if (tid == 0)
        __hip_atomic_fetch_add(prog + mt, 1u, __ATOMIC_RELEASE,
                               __HIP_MEMORY_SCOPE_AGENT);
    }
    return;
  }

  // ---------------------------------------------------------- scan role ----
  if (tid >= 64) return;  // one wave; rest of the block exits, CU stays clean
  __builtin_amdgcn_s_setprio(3);

  const int b = blockIdx.x;
  const int lane = tid;
  float* base = out + (size_t)b * (size_t)(T * Hh);
  const int h0 = lane * 4;
  const int h1 = 256 + lane * 4;

  float4 tav0 = *(const float4*)(ta + h0);
  float4 tav1 = *(const float4*)(ta + h1);
  float tac[8] = {tav0.x, tav0.y, tav0.z, tav0.w,
                  tav1.x, tav1.y, tav1.z, tav1.w};

  // chunk (b,ch) ready when prog[b*8+ch] == 2 (bn = 0,1 tiles done)
#define WAIT_CHUNK(idxc)                                                     \
  {                                                                          \
    unsigned* wp = prog + (idxc);                                            \
    while (__hip_atomic_load(wp, __ATOMIC_RELAXED,                           \
                             __HIP_MEMORY_SCOPE_AGENT) < 2u) {               \
      __builtin_amdgcn_s_sleep(2);                                           \
    }                                                                        \
    __builtin_amdgcn_fence(__ATOMIC_ACQUIRE, "agent");                       \
  }

  // Double-buffered 8-step register groups. All indices compile-time.
  float4 pA0[8], pB0[8], pA1[8], pB1[8];
  float cc[8], mr[8];
  bool fire[8];
#pragma unroll
  for (int i = 0; i < 8; ++i) fire[i] = false;

#define LOAD1(NA, NB, u, t)                                                  \
  NA[u] = *(const float4*)(base + (size_t)(t) * Hh + h0);                    \
  NB[u] = *(const float4*)(base + (size_t)(t) * Hh + h1);

#define STEPX(CA, CB, u, t, NXA, NXB, SPEC)                                  \
  {                                                                          \
    const float xu_[8] = {CA[u].x, CA[u].y, CA[u].z, CA[u].w,                \
                          CB[u].x, CB[u].y, CB[u].z, CB[u].w};               \
    _Pragma("unroll")                                                        \
    for (int i = 0; i < 8; ++i) mr[i] = fire[i] ? xu_[i] : cc[i];            \
    float s_ = ((mr[0] + mr[1]) + (mr[2] + mr[3])) +                         \
               ((mr[4] + mr[5]) + (mr[6] + mr[7]));                          \
    float q_ = ((fmaf(mr[0], mr[0], mr[1] * mr[1])) +                        \
                (fmaf(mr[2], mr[2], mr[3] * mr[3]))) +                       \
               ((fmaf(mr[4], mr[4], mr[5] * mr[5])) +                        \
                (fmaf(mr[6], mr[6], mr[7] * mr[7])));                        \
    if (SPEC) { /* speculative next-step update, overlaps reduce */          \
      const float4 nxa_ = (NXA), nxb_ = (NXB);                               \
      const float xn_[8] = {nxa_.x, nxa_.y, nxa_.z, nxa_.w,                  \
                            nxb_.x, nxb_.y, nxb_.z, nxb_.w};                 \
      _Pragma("unroll")                                                      \
      for (int i = 0; i < 8; ++i) cc[i] = fmaf(ALPHA_F, mr[i], xn_[i]);      \
    }                                                                        \
    s_ = dpp_reduce(s_);                                                     \
    q_ = dpp_reduce(q_);                                                     \
    float var_ = fmaf(s_ * s_, -(1.0f / Hh), q_) * (1.0f / (Hh - 1));        \
    var_ = fmaxf(var_, 0.f);                                                 \
    float sdl_ = __builtin_amdgcn_sqrtf(var_); /* lane 63 valid */           \
    const float sd_ = __builtin_bit_cast(                                    \
        float,                                                               \
        __builtin_amdgcn_readlane(__builtin_bit_cast(int, sdl_), 63));       \
    float sp_[8];                                                            \
    _Pragma("unroll")                                                        \
    for (int i = 0; i < 8; ++i) {                                            \
      fire[i] = mr[i] >= fmaf(0.1f, sd_, tac[i]);                            \
      sp_[i] = fire[i] ? 1.f : 0.f;                                          \
    }                                                                        \
    *(float4*)(base + (size_t)(t) * Hh + h0) =                               \
        make_float4(sp_[0], sp_[1], sp_[2], sp_[3]);                         \
    *(float4*)(base + (size_t)(t) * Hh + h1) =                               \
        make_float4(sp_[4], sp_[5], sp_[6], sp_[7]);                         \
  }

// One group: (optionally) issue next-group loads into NA/NB FIRST, then
// compute 8 steps from CA/CB. u=7's speculation reads NA[0]/NB[0] -- the
// load issued ~7 steps earlier in this same group (covered).
#define GROUP(CA, CB, NA, NB, T0, PF, LASTG)                                 \
  {                                                                          \
    if (PF) {                                                                \
      LOAD1(NA, NB, 0, (T0) + 8)  LOAD1(NA, NB, 1, (T0) + 9)                 \
      LOAD1(NA, NB, 2, (T0) + 10) LOAD1(NA, NB, 3, (T0) + 11)                \
      LOAD1(NA, NB, 4, (T0) + 12) LOAD1(NA, NB, 5, (T0) + 13)                \
      LOAD1(NA, NB, 6, (T0) + 14) LOAD1(NA, NB, 7, (T0) + 15)                \
    }                                                                        \
    STEPX(CA, CB, 0, (T0) + 0, CA[1], CB[1], 1)                              \
    STEPX(CA, CB, 1, (T0) + 1, CA[2], CB[2], 1)                              \
    STEPX(CA, CB, 2, (T0) + 2, CA[3], CB[3], 1)                              \
    STEPX(CA, CB, 3, (T0) + 3, CA[4], CB[4], 1)                              \
    STEPX(CA, CB, 4, (T0) + 4, CA[5], CB[5], 1)                              \
    STEPX(CA, CB, 5, (T0) + 5, CA[6], CB[6], 1)                              \
    STEPX(CA, CB, 6, (T0) + 6, CA[7], CB[7], 1)                              \
    STEPX(CA, CB, 7, (T0) + 7, NA[0], NB[0], !(LASTG))                       \
  }

  WAIT_CHUNK(b * 8);
  // prologue: buf0 <- steps 0..7
  LOAD1(pA0, pB0, 0, 0) LOAD1(pA0, pB0, 1, 1)
  LOAD1(pA0, pB0, 2, 2) LOAD1(pA0, pB0, 3, 3)
  LOAD1(pA0, pB0, 4, 4) LOAD1(pA0, pB0, 5, 5)
  LOAD1(pA0, pB0, 6, 6) LOAD1(pA0, pB0, 7, 7)
  // cc for t=0 is x_0 (mem starts at 0)
  cc[0] = pA0[0].x; cc[1] = pA0[0].y; cc[2] = pA0[0].z; cc[3] = pA0[0].w;
  cc[4] = pB0[0].x; cc[5] = pB0[0].y; cc[6] = pB0[0].z; cc[7] = pB0[0].w;

  for (int gp = 0; gp < 63; ++gp) {
    const int t0 = gp << 4;
    GROUP(pA0, pB0, pA1, pB1, t0, true, false)
    // GROUPB's prefetch (steps t0+16..t0+23) crosses a chunk boundary iff
    // (t0+16) % 128 == 0, i.e. gp % 8 == 7. Gate it. (uniform branch)
    if ((gp & 7) == 7) WAIT_CHUNK(b * 8 + ((t0 + 16) >> 7));
    GROUP(pA1, pB1, pA0, pB0, t0 + 8, true, false)
  }
  GROUP(pA0, pB0, pA1, pB1, 1008, true, false)
  GROUP(pA1, pB1, pA0, pB0, 1016, false, true)

#undef GROUP
#undef STEPX
#undef LOAD1
#undef WAIT_CHUNK

  float mf[8];
#pragma unroll
  for (int i = 0; i < 8; ++i) mf[i] = fire[i] ? 0.f : mr[i];
  *(float4*)(memout + (size_t)b * Hh + h0) = make_float4(mf[0], mf[1], mf[2], mf[3]);
  *(float4*)(memout + (size_t)b * Hh + h1) = make_float4(mf[4], mf[5], mf[6], mf[7]);
}

// ------------------------------------------------- fallback (two-kernel) ----
__global__ __launch_bounds__(256) void gemm_kernel(
    const float* __restrict__ X, const float* __restrict__ W,
    const float* __restrict__ bias, float* __restrict__ out) {
  const int bn = blockIdx.x, bm = blockIdx.y;
  __shared__ float As[BK][BM + 4];
  __shared__ float Bs[BK][BM + 4];
  const int tid = threadIdx.x, tm = tid >> 4, tn = tid & 15;
  float acc[8][8];
#pragma unroll
  for (int i = 0; i < 8; ++i)
#pragma unroll
    for (int j = 0; j < 8; ++j) acc[i][j] = 0.f;
  const int rowA = bm * BM, rowB = bn * BM;
  for (int k0 = 0; k0 < D; k0 += BK) {
    __syncthreads();
#pragma unroll
    for (int i = 0; i < 2; ++i) {
      const int f = tid * 2 + i, r = f >> 2, c4 = (f & 3) << 2;
      float4 a = *(const float4*)(X + (size_t)(rowA + r) * D + k0 + c4);
      As[c4 + 0][r] = a.x; As[c4 + 1][r] = a.y;
      As[c4 + 2][r] = a.z; As[c4 + 3][r] = a.w;
      float4 w = *(const float4*)(W + (size_t)(rowB + r) * D + k0 + c4);
      Bs[c4 + 0][r] = w.x; Bs[c4 + 1][r] = w.y;
      Bs[c4 + 2][r] = w.z; Bs[c4 + 3][r] = w.w;
    }
    __syncthreads();
#pragma unroll
    for (int k = 0; k < BK; ++k) {
      float4 a0 = *(const float4*)&As[k][tm * 4];
      float4 a1 = *(const float4*)&As[k][64 + tm * 4];
      float4 b0 = *(const float4*)&Bs[k][tn * 4];
      float4 b1 = *(const float4*)&Bs[k][64 + tn * 4];
      float av[8] = {a0.x, a0.y, a0.z, a0.w, a1.x, a1.y, a1.z, a1.w};
      float bv[8] = {b0.x, b0.y, b0.z, b0.w, b1.x, b1.y, b1.z, b1.w};
#pragma unroll
      for (int i = 0; i < 8; ++i)
#pragma unroll
        for (int j = 0; j < 8; ++j)
          acc[i][j] = fmaf(av[i], bv[j], acc[i][j]);
    }
  }
  const int c0 = rowB + tn * 4, c1 = rowB + 64 + tn * 4;
  float4 bb0 = *(const float4*)(bias + c0);
  float4 bb1 = *(const float4*)(bias + c1);
  float bc[8] = {bb0.x, bb0.y, bb0.z, bb0.w, bb1.x, bb1.y, bb1.z, bb1.w};
#pragma unroll
  for (int i = 0; i < 8; ++i) {
    const int r = rowA + ((i < 4) ? (tm * 4 + i) : (64 + tm * 4 + (i - 4)));
    float4 v0, v1;
    v0.x = acc[i][0] + bc[0]; v0.y = acc[i][1] + bc[1];
    v0.z = acc[i][2] + bc[2]; v0.w = acc[i][3] + bc[3];
    v1.x = acc[i][4] + bc[4]; v1.y = acc[i][5] + bc[5];
    v1.z = acc[i][6] + bc[6]; v1.w = acc[i][7] + bc[7];
    *(float4*)(out + (size_t)r * Hh + c0) = v0;
    *(float4*)(out + (size_t)r * Hh + c1) = v1;
  }
}

__global__ __launch_bounds__(64) void scan_kernel(
    float* __restrict__ xs, const float* __restrict__ ta,
    float* __restrict__ memout) {
  const int b = blockIdx.x, lane = threadIdx.x;
  float* base = xs + (size_t)b * (size_t)(T * Hh);
  const int h0 = lane * 4, h1 = 256 + lane * 4;
  float4 tav0 = *(const float4*)(ta + h0);
  float4 tav1 = *(const float4*)(ta + h1);
  float tac[8] = {tav0.x, tav0.y, tav0.z, tav0.w,
                  tav1.x, tav1.y, tav1.z, tav1.w};
  float4 pa[4], pb[4];
#pragma unroll
  for (int u = 0; u < 4; ++u) {
    pa[u] = *(const float4*)(base + (size_t)u * Hh + h0);
    pb[u] = *(const float4*)(base + (size_t)u * Hh + h1);
  }
  float xc[8], cc[8], mr[8];
  bool fire[8];
  {
    const float4 a = pa[0], bq = pb[0];
    xc[0] = a.x; xc[1] = a.y; xc[2] = a.z; xc[3] = a.w;
    xc[4] = bq.x; xc[5] = bq.y; xc[6] = bq.z; xc[7] = bq.w;
  }
#pragma unroll
  for (int i = 0; i < 8; ++i) { cc[i] = xc[i]; fire[i] = false; }
#pragma unroll 4
  for (int t = 0; t < T; ++t) {
    const int u = t & 3;
    if (t + 4 < T) {
      pa[u] = *(const float4*)(base + (size_t)(t + 4) * Hh + h0);
      pb[u] = *(const float4*)(base + (size_t)(t + 4) * Hh + h1);
    }
#pragma unroll
    for (int i = 0; i < 8; ++i) mr[i] = fire[i] ? xc[i] : cc[i];
    float s = ((mr[0] + mr[1]) + (mr[2] + mr[3])) +
              ((mr[4] + mr[5]) + (mr[6] + mr[7]));
    float q = ((mr[0] * mr[0] + mr[1] * mr[1]) +
               (mr[2] * mr[2] + mr[3] * mr[3])) +
              ((mr[4] * mr[4] + mr[5] * mr[5]) +
               (mr[6] * mr[6] + mr[7] * mr[7]));
    {
      const float4 na = pa[(u + 1) & 3];
      const float4 nb = pb[(u + 1) & 3];
      xc[0] = na.x; xc[1] = na.y; xc[2] = na.z; xc[3] = na.w;
      xc[4] = nb.x; xc[5] = nb.y; xc[6] = nb.z; xc[7] = nb.w;
#pragma unroll
      for (int i = 0; i < 8; ++i) cc[i] = fmaf(ALPHA_F, mr[i], xc[i]);
    }
    s = dpp_reduce(s);
    q = dpp_reduce(q);
    float var = fmaxf((q - s * s * (1.0f / Hh)) * (1.0f / (Hh - 1)), 0.f);
    float sdl = __builtin_amdgcn_sqrtf(var);
    const float sd = __builtin_bit_cast(
        float, __builtin_amdgcn_readlane(__builtin_bit_cast(int, sdl), 63));
    float sp[8];
#pragma unroll
    for (int i = 0; i < 8; ++i) {
      fire[i] = mr[i] >= fmaf(0.1f, sd, tac[i]);
      sp[i] = fire[i] ? 1.f : 0.f;
    }
    *(float4*)(base + (size_t)t * Hh + h0) = make_float4(sp[0], sp[1], sp[2], sp[3]);
    *(float4*)(base + (size_t)t * Hh + h1) = make_float4(sp[4], sp[5], sp[6], sp[7]);
  }
  float mf[8];
#pragma unroll
  for (int i = 0; i < 8; ++i) mf[i] = fire[i] ? 0.f : mr[i];
  *(float4*)(memout + (size_t)b * Hh + h0) = make_float4(mf[0], mf[1], mf[2], mf[3]);
  *(float4*)(memout + (size_t)b * Hh + h1) = make_float4(mf[4], mf[5], mf[6], mf[7]);
}

// -------------------------------------------------------------- launch ----
extern "C" void kernel_launch(void* const* d_in, const int* in_sizes, int n_in,
                              void* d_out, int out_size, void* d_ws,
                              size_t ws_size, hipStream_t stream) {
  const float* x    = (const float*)d_in[0];
  const float* W    = (const float*)d_in[1];
  const float* bias = (const float*)d_in[2];
  const float* ta   = (const float*)d_in[3];

  float* out    = (float*)d_out;
  float* spikes = out;
  float* memout = out + (size_t)Bb * T * Hh;

  if (ws_size >= 257 * sizeof(unsigned)) {
    unsigned* ws = (unsigned*)d_ws;
    zero_ws_kernel<<<dim3(1), dim3(512), 0, stream>>>(ws);
    fused_kernel<<<dim3(NBLOCKS), dim3(512), 0, stream>>>(
        x, W, bias, ta, spikes, memout, ws);
  } else {
    dim3 ggrid(Hh / 128, M / BM);
    gemm_kernel<<<ggrid, dim3(256), 0, stream>>>(x, W, bias, spikes);
    scan_kernel<<<dim3(Bb), dim3(64), 0, stream>>>(spikes, ta, memout);
  }
}

// Round 8
// 300.013 us; speedup vs baseline: 1.3844x; 1.0826x over previous
//
#include <hip/hip_runtime.h>

// SpikingNeuronLayer fused producer/consumer, R8:
//   grid = 256 blocks x 512 threads -> 1 block/CU (round-robin placement).
//   blocks 0..31   : scan role, wave 0 only (R7's batch double-buffered
//                    register groups -- unchanged).
//   blocks 32..255 : GEMM workers, R8: software-pipelined k-loop --
//                    register prefetch of the next BK-slab + double-buffered
//                    LDS + ONE barrier per staging-iter. Global-load latency
//                    hides under the 4096-cy compute window; ds_writes of one
//                    wave overlap other waves' FMA.
// xlin lands in d_out's spike region and is overwritten in place by the scan.

#define ALPHA_F 0.95122942450071402f  // float(exp(-1/20))

constexpr int Bb = 32, T = 1024, D = 512, Hh = 512;
constexpr int M = Bb * T;              // 32768
constexpr int NSCAN = 32;
constexpr int NBLOCKS = 256;           // 32 scan + 224 GEMM workers
constexpr int NTILES = 512;            // (M/128) * (H/256)

#define BM 128
#define BN 256
#define BK 16
#define LDA (BM + 4)                   // 132
#define LDB (BN + 4)                   // 260

// ------------------------------------------------------------ DPP reduce ----
template <int CTRL>
__device__ __forceinline__ float dpp_add(float v) {
  int s = __builtin_amdgcn_update_dpp(0, __builtin_bit_cast(int, v),
                                      CTRL, 0xF, 0xF, true);
  return v + __builtin_bit_cast(float, s);
}

// 64-lane sum; result valid in lane 63 only (caller readlanes).
__device__ __forceinline__ float dpp_reduce(float v) {
  v = dpp_add<0x111>(v);  // row_shr:1
  v = dpp_add<0x112>(v);  // row_shr:2
  v = dpp_add<0x114>(v);  // row_shr:4
  v = dpp_add<0x118>(v);  // row_shr:8
  v = dpp_add<0x142>(v);  // row_bcast15
  v = dpp_add<0x143>(v);  // row_bcast31 -> lane 63 = total
  return v;
}

// ------------------------------------------------------------- zero ws ----
__global__ void zero_ws_kernel(unsigned* ws) {
  if (threadIdx.x < 257) ws[threadIdx.x] = 0;  // prog[256] + ticket
}

// ------------------------------------------------------------ fused ----
__global__ __launch_bounds__(512) void fused_kernel(
    const float* __restrict__ X,     // [M, D]
    const float* __restrict__ W,     // [H, D]
    const float* __restrict__ bias,  // [H]
    const float* __restrict__ ta,    // [H]
    float* out,                      // [M, H]: xlin then spikes (in place)
    float* memout,                   // [B, H]
    unsigned* ws)                    // prog[256] (per-mt), ticket
{
  unsigned* prog = ws;
  unsigned* ticket = ws + 256;
  const int tid = threadIdx.x;

  if (blockIdx.x >= NSCAN) {
    // -------------------- GEMM role (persistent, ticketed, pipelined) -----
    __shared__ float As[2][BK][LDA];   // 16.5 KB
    __shared__ float Bs[2][BK][LDB];   // 32.5 KB
    __shared__ unsigned s_g;
    const int tm = tid >> 5;   // 0..15
    const int tn = tid & 31;   // 0..31
    const int sr = tid >> 2;          // staging row 0..127
    const int sc4 = (tid & 3) << 2;   // staging col 0,4,8,12

    float4 ra, rb0, rb1;  // staged slab (registers)

#define GLOAD(k0)                                                            \
  {                                                                          \
    ra  = *(const float4*)(X + (size_t)(rowA + sr) * D + (k0) + sc4);        \
    rb0 = *(const float4*)(W + (size_t)(rowB + sr) * D + (k0) + sc4);        \
    rb1 = *(const float4*)(W + (size_t)(rowB + 128 + sr) * D + (k0) + sc4);  \
  }

#define SWRITE(bf)                                                           \
  {                                                                          \
    As[bf][sc4 + 0][sr] = ra.x; As[bf][sc4 + 1][sr] = ra.y;                  \
    As[bf][sc4 + 2][sr] = ra.z; As[bf][sc4 + 3][sr] = ra.w;                  \
    Bs[bf][sc4 + 0][sr] = rb0.x; Bs[bf][sc4 + 1][sr] = rb0.y;                \
    Bs[bf][sc4 + 2][sr] = rb0.z; Bs[bf][sc4 + 3][sr] = rb0.w;                \
    Bs[bf][sc4 + 0][sr + 128] = rb1.x; Bs[bf][sc4 + 1][sr + 128] = rb1.y;    \
    Bs[bf][sc4 + 2][sr + 128] = rb1.z; Bs[bf][sc4 + 3][sr + 128] = rb1.w;    \
  }

    for (;;) {
      __syncthreads();  // protects s_g WAR + LDS reuse across tiles
      if (tid == 0)
        s_g = __hip_atomic_fetch_add(ticket, 1u, __ATOMIC_RELAXED,
                                     __HIP_MEMORY_SCOPE_AGENT);
      __syncthreads();
      const unsigned g = s_g;
      if (g >= NTILES) break;  // uniform
      // ch-major decode: g = ch*64 + idx ; mt = (idx>>1)*8 + ch ; bn = idx&1
      const int chg = (int)(g >> 6);          // 0..7 (time-chunk class)
      const int idx = (int)(g & 63u);
      const int mt  = (idx >> 1) * 8 + chg;   // 0..255 (128-row band)
      const int bn  = idx & 1;
      const int rowA = mt * BM;
      const int rowB = bn * BN;

      float acc[8][8];
#pragma unroll
      for (int i = 0; i < 8; ++i)
#pragma unroll
        for (int j = 0; j < 8; ++j) acc[i][j] = 0.f;

      GLOAD(0)
      int cur = 0;
      for (int k0 = 0; k0 < D; k0 += BK) {
        SWRITE(cur)        // compiler inserts vmcnt wait before first write
        __syncthreads();   // buf[cur] ready for all
        if (k0 + BK < D) GLOAD(k0 + BK)  // in flight during compute below
#pragma unroll
        for (int k = 0; k < BK; ++k) {
          float4 a0 = *(const float4*)&As[cur][k][tm * 4];
          float4 a1 = *(const float4*)&As[cur][k][64 + tm * 4];
          float4 b0 = *(const float4*)&Bs[cur][k][tn * 4];
          float4 b1 = *(const float4*)&Bs[cur][k][128 + tn * 4];
          float av[8] = {a0.x, a0.y, a0.z, a0.w, a1.x, a1.y, a1.z, a1.w};
          float bv[8] = {b0.x, b0.y, b0.z, b0.w, b1.x, b1.y, b1.z, b1.w};
#pragma unroll
          for (int i = 0; i < 8; ++i)
#pragma unroll
            for (int j = 0; j < 8; ++j)
              acc[i][j] = fmaf(av[i], bv[j], acc[i][j]);
        }
        cur ^= 1;
        // no second barrier: buf[cur^1] (about to be written next iter) was
        // last read at iter-2's compute, and every wave passed this iter's
        // barrier after that compute -> WAR safe with ONE barrier/iter.
      }

      const int c0 = rowB + tn * 4;
      const int c1 = rowB + 128 + tn * 4;
      float4 bb0 = *(const float4*)(bias + c0);
      float4 bb1 = *(const float4*)(bias + c1);
      float bc[8] = {bb0.x, bb0.y, bb0.z, bb0.w, bb1.x, bb1.y, bb1.z, bb1.w};
#pragma unroll
      for (int i = 0; i < 8; ++i) {
        const int r = rowA + ((i < 4) ? (tm * 4 + i) : (64 + tm * 4 + (i - 4)));
        float4 v0, v1;
        v0.x = acc[i][0] + bc[0]; v0.y = acc[i][1] + bc[1];
        v0.z = acc[i][2] + bc[2]; v0.w = acc[i][3] + bc[3];
        v1.x = acc[i][4] + bc[4]; v1.y = acc[i][5] + bc[5];
        v1.z = acc[i][6] + bc[6]; v1.w = acc[i][7] + bc[7];
        *(float4*)(out + (size_t)r * Hh + c0) = v0;
        *(float4*)(out + (size_t)r * Hh + c1) = v1;
      }
      __syncthreads();  // barrier drain: all waves' stores at vmcnt(0)
      if (tid == 0)
        __hip_atomic_fetch_add(prog + mt, 1u, __ATOMIC_RELEASE,
                               __HIP_MEMORY_SCOPE_AGENT);
    }
#undef GLOAD
#undef SWRITE
    return;
  }

  // ---------------------------------------------------------- scan role ----
  if (tid >= 64) return;  // one wave; rest of the block exits, CU stays clean
  __builtin_amdgcn_s_setprio(3);

  const int b = blockIdx.x;
  const int lane = tid;
  float* base = out + (size_t)b * (size_t)(T * Hh);
  const int h0 = lane * 4;
  const int h1 = 256 + lane * 4;

  float4 tav0 = *(const float4*)(ta + h0);
  float4 tav1 = *(const float4*)(ta + h1);
  float tac[8] = {tav0.x, tav0.y, tav0.z, tav0.w,
                  tav1.x, tav1.y, tav1.z, tav1.w};

  // chunk (b,ch) ready when prog[b*8+ch] == 2 (bn = 0,1 tiles done)
#define WAIT_CHUNK(idxc)                                                     \
  {                                                                          \
    unsigned* wp = prog + (idxc);                                            \
    while (__hip_atomic_load(wp, __ATOMIC_RELAXED,                           \
                             __HIP_MEMORY_SCOPE_AGENT) < 2u) {               \
      __builtin_amdgcn_s_sleep(2);                                           \
    }                                                                        \
    __builtin_amdgcn_fence(__ATOMIC_ACQUIRE, "agent");                       \
  }

  // Double-buffered 8-step register groups. All indices compile-time.
  float4 pA0[8], pB0[8], pA1[8], pB1[8];
  float cc[8], mr[8];
  bool fire[8];
#pragma unroll
  for (int i = 0; i < 8; ++i) fire[i] = false;

#define LOAD1(NA, NB, u, t)                                                  \
  NA[u] = *(const float4*)(base + (size_t)(t) * Hh + h0);                    \
  NB[u] = *(const float4*)(base + (size_t)(t) * Hh + h1);

#define STEPX(CA, CB, u, t, NXA, NXB, SPEC)                                  \
  {                                                                          \
    const float xu_[8] = {CA[u].x, CA[u].y, CA[u].z, CA[u].w,                \
                          CB[u].x, CB[u].y, CB[u].z, CB[u].w};               \
    _Pragma("unroll")                                                        \
    for (int i = 0; i < 8; ++i) mr[i] = fire[i] ? xu_[i] : cc[i];            \
    float s_ = ((mr[0] + mr[1]) + (mr[2] + mr[3])) +                         \
               ((mr[4] + mr[5]) + (mr[6] + mr[7]));                          \
    float q_ = ((fmaf(mr[0], mr[0], mr[1] * mr[1])) +                        \
                (fmaf(mr[2], mr[2], mr[3] * mr[3]))) +                       \
               ((fmaf(mr[4], mr[4], mr[5] * mr[5])) +                        \
                (fmaf(mr[6], mr[6], mr[7] * mr[7])));                        \
    if (SPEC) { /* speculative next-step update, overlaps reduce */          \
      const float4 nxa_ = (NXA), nxb_ = (NXB);                               \
      const float xn_[8] = {nxa_.x, nxa_.y, nxa_.z, nxa_.w,                  \
                            nxb_.x, nxb_.y, nxb_.z, nxb_.w};                 \
      _Pragma("unroll")                                                      \
      for (int i = 0; i < 8; ++i) cc[i] = fmaf(ALPHA_F, mr[i], xn_[i]);      \
    }                                                                        \
    s_ = dpp_reduce(s_);                                                     \
    q_ = dpp_reduce(q_);                                                     \
    float var_ = fmaf(s_ * s_, -(1.0f / Hh), q_) * (1.0f / (Hh - 1));        \
    var_ = fmaxf(var_, 0.f);                                                 \
    float sdl_ = __builtin_amdgcn_sqrtf(var_); /* lane 63 valid */           \
    const float sd_ = __builtin_bit_cast(                                    \
        float,                                                               \
        __builtin_amdgcn_readlane(__builtin_bit_cast(int, sdl_), 63));       \
    float sp_[8];                                                            \
    _Pragma("unroll")                                                        \
    for (int i = 0; i < 8; ++i) {                                            \
      fire[i] = mr[i] >= fmaf(0.1f, sd_, tac[i]);                            \
      sp_[i] = fire[i] ? 1.f : 0.f;                                          \
    }                                                                        \
    *(float4*)(base + (size_t)(t) * Hh + h0) =                               \
        make_float4(sp_[0], sp_[1], sp_[2], sp_[3]);                         \
    *(float4*)(base + (size_t)(t) * Hh + h1) =                               \
        make_float4(sp_[4], sp_[5], sp_[6], sp_[7]);                         \
  }

// One group: (optionally) issue next-group loads into NA/NB FIRST, then
// compute 8 steps from CA/CB. u=7's speculation reads NA[0]/NB[0] -- the
// load issued ~7 steps earlier in this same group (covered).
#define GROUP(CA, CB, NA, NB, T0, PF, LASTG)                                 \
  {                                                                          \
    if (PF) {                                                                \
      LOAD1(NA, NB, 0, (T0) + 8)  LOAD1(NA, NB, 1, (T0) + 9)                 \
      LOAD1(NA, NB, 2, (T0) + 10) LOAD1(NA, NB, 3, (T0) + 11)                \
      LOAD1(NA, NB, 4, (T0) + 12) LOAD1(NA, NB, 5, (T0) + 13)                \
      LOAD1(NA, NB, 6, (T0) + 14) LOAD1(NA, NB, 7, (T0) + 15)                \
    }                                                                        \
    STEPX(CA, CB, 0, (T0) + 0, CA[1], CB[1], 1)                              \
    STEPX(CA, CB, 1, (T0) + 1, CA[2], CB[2], 1)                              \
    STEPX(CA, CB, 2, (T0) + 2, CA[3], CB[3], 1)                              \
    STEPX(CA, CB, 3, (T0) + 3, CA[4], CB[4], 1)                              \
    STEPX(CA, CB, 4, (T0) + 4, CA[5], CB[5], 1)                              \
    STEPX(CA, CB, 5, (T0) + 5, CA[6], CB[6], 1)                              \
    STEPX(CA, CB, 6, (T0) + 6, CA[7], CB[7], 1)                              \
    STEPX(CA, CB, 7, (T0) + 7, NA[0], NB[0], !(LASTG))                       \
  }

  WAIT_CHUNK(b * 8);
  // prologue: buf0 <- steps 0..7
  LOAD1(pA0, pB0, 0, 0) LOAD1(pA0, pB0, 1, 1)
  LOAD1(pA0, pB0, 2, 2) LOAD1(pA0, pB0, 3, 3)
  LOAD1(pA0, pB0, 4, 4) LOAD1(pA0, pB0, 5, 5)
  LOAD1(pA0, pB0, 6, 6) LOAD1(pA0, pB0, 7, 7)
  // cc for t=0 is x_0 (mem starts at 0)
  cc[0] = pA0[0].x; cc[1] = pA0[0].y; cc[2] = pA0[0].z; cc[3] = pA0[0].w;
  cc[4] = pB0[0].x; cc[5] = pB0[0].y; cc[6] = pB0[0].z; cc[7] = pB0[0].w;

  for (int gp = 0; gp < 63; ++gp) {
    const int t0 = gp << 4;
    GROUP(pA0, pB0, pA1, pB1, t0, true, false)
    // GROUPB's prefetch (steps t0+16..t0+23) crosses a chunk boundary iff
    // (t0+16) % 128 == 0, i.e. gp % 8 == 7. Gate it. (uniform branch)
    if ((gp & 7) == 7) WAIT_CHUNK(b * 8 + ((t0 + 16) >> 7));
    GROUP(pA1, pB1, pA0, pB0, t0 + 8, true, false)
  }
  GROUP(pA0, pB0, pA1, pB1, 1008, true, false)
  GROUP(pA1, pB1, pA0, pB0, 1016, false, true)

#undef GROUP
#undef STEPX
#undef LOAD1
#undef WAIT_CHUNK

  float mf[8];
#pragma unroll
  for (int i = 0; i < 8; ++i) mf[i] = fire[i] ? 0.f : mr[i];
  *(float4*)(memout + (size_t)b * Hh + h0) = make_float4(mf[0], mf[1], mf[2], mf[3]);
  *(float4*)(memout + (size_t)b * Hh + h1) = make_float4(mf[4], mf[5], mf[6], mf[7]);
}

// ------------------------------------------------- fallback (two-kernel) ----
__global__ __launch_bounds__(256) void gemm_kernel(
    const float* __restrict__ X, const float* __restrict__ W,
    const float* __restrict__ bias, float* __restrict__ out) {
  const int bn = blockIdx.x, bm = blockIdx.y;
  __shared__ float As[BK][BM + 4];
  __shared__ float Bs[BK][BM + 4];
  const int tid = threadIdx.x, tm = tid >> 4, tn = tid & 15;
  float acc[8][8];
#pragma unroll
  for (int i = 0; i < 8; ++i)
#pragma unroll
    for (int j = 0; j < 8; ++j) acc[i][j] = 0.f;
  const int rowA = bm * BM, rowB = bn * BM;
  for (int k0 = 0; k0 < D; k0 += BK) {
    __syncthreads();
#pragma unroll
    for (int i = 0; i < 2; ++i) {
      const int f = tid * 2 + i, r = f >> 2, c4 = (f & 3) << 2;
      float4 a = *(const float4*)(X + (size_t)(rowA + r) * D + k0 + c4);
      As[c4 + 0][r] = a.x; As[c4 + 1][r] = a.y;
      As[c4 + 2][r] = a.z; As[c4 + 3][r] = a.w;
      float4 w = *(const float4*)(W + (size_t)(rowB + r) * D + k0 + c4);
      Bs[c4 + 0][r] = w.x; Bs[c4 + 1][r] = w.y;
      Bs[c4 + 2][r] = w.z; Bs[c4 + 3][r] = w.w;
    }
    __syncthreads();
#pragma unroll
    for (int k = 0; k < BK; ++k) {
      float4 a0 = *(const float4*)&As[k][tm * 4];
      float4 a1 = *(const float4*)&As[k][64 + tm * 4];
      float4 b0 = *(const float4*)&Bs[k][tn * 4];
      float4 b1 = *(const float4*)&Bs[k][64 + tn * 4];
      float av[8] = {a0.x, a0.y, a0.z, a0.w, a1.x, a1.y, a1.z, a1.w};
      float bv[8] = {b0.x, b0.y, b0.z, b0.w, b1.x, b1.y, b1.z, b1.w};
#pragma unroll
      for (int i = 0; i < 8; ++i)
#pragma unroll
        for (int j = 0; j < 8; ++j)
          acc[i][j] = fmaf(av[i], bv[j], acc[i][j]);
    }
  }
  const int c0 = rowB + tn * 4, c1 = rowB + 64 + tn * 4;
  float4 bb0 = *(const float4*)(bias + c0);
  float4 bb1 = *(const float4*)(bias + c1);
  float bc[8] = {bb0.x, bb0.y, bb0.z, bb0.w, bb1.x, bb1.y, bb1.z, bb1.w};
#pragma unroll
  for (int i = 0; i < 8; ++i) {
    const int r = rowA + ((i < 4) ? (tm * 4 + i) : (64 + tm * 4 + (i - 4)));
    float4 v0, v1;
    v0.x = acc[i][0] + bc[0]; v0.y = acc[i][1] + bc[1];
    v0.z = acc[i][2] + bc[2]; v0.w = acc[i][3] + bc[3];
    v1.x = acc[i][4] + bc[4]; v1.y = acc[i][5] + bc[5];
    v1.z = acc[i][6] + bc[6]; v1.w = acc[i][7] + bc[7];
    *(float4*)(out + (size_t)r * Hh + c0) = v0;
    *(float4*)(out + (size_t)r * Hh + c1) = v1;
  }
}

__global__ __launch_bounds__(64) void scan_kernel(
    float* __restrict__ xs, const float* __restrict__ ta,
    float* __restrict__ memout) {
  const int b = blockIdx.x, lane = threadIdx.x;
  float* base = xs + (size_t)b * (size_t)(T * Hh);
  const int h0 = lane * 4, h1 = 256 + lane * 4;
  float4 tav0 = *(const float4*)(ta + h0);
  float4 tav1 = *(const float4*)(ta + h1);
  float tac[8] = {tav0.x, tav0.y, tav0.z, tav0.w,
                  tav1.x, tav1.y, tav1.z, tav1.w};
  float4 pa[4], pb[4];
#pragma unroll
  for (int u = 0; u < 4; ++u) {
    pa[u] = *(const float4*)(base + (size_t)u * Hh + h0);
    pb[u] = *(const float4*)(base + (size_t)u * Hh + h1);
  }
  float xc[8], cc[8], mr[8];
  bool fire[8];
  {
    const float4 a = pa[0], bq = pb[0];
    xc[0] = a.x; xc[1] = a.y; xc[2] = a.z; xc[3] = a.w;
    xc[4] = bq.x; xc[5] = bq.y; xc[6] = bq.z; xc[7] = bq.w;
  }
#pragma unroll
  for (int i = 0; i < 8; ++i) { cc[i] = xc[i]; fire[i] = false; }
#pragma unroll 4
  for (int t = 0; t < T; ++t) {
    const int u = t & 3;
    if (t + 4 < T) {
      pa[u] = *(const float4*)(base + (size_t)(t + 4) * Hh + h0);
      pb[u] = *(const float4*)(base + (size_t)(t + 4) * Hh + h1);
    }
#pragma unroll
    for (int i = 0; i < 8; ++i) mr[i] = fire[i] ? xc[i] : cc[i];
    float s = ((mr[0] + mr[1]) + (mr[2] + mr[3])) +
              ((mr[4] + mr[5]) + (mr[6] + mr[7]));
    float q = ((mr[0] * mr[0] + mr[1] * mr[1]) +
               (mr[2] * mr[2] + mr[3] * mr[3])) +
              ((mr[4] * mr[4] + mr[5] * mr[5]) +
               (mr[6] * mr[6] + mr[7] * mr[7]));
    {
      const float4 na = pa[(u + 1) & 3];
      const float4 nb = pb[(u + 1) & 3];
      xc[0] = na.x; xc[1] = na.y; xc[2] = na.z; xc[3] = na.w;
      xc[4] = nb.x; xc[5] = nb.y; xc[6] = nb.z; xc[7] = nb.w;
#pragma unroll
      for (int i = 0; i < 8; ++i) cc[i] = fmaf(ALPHA_F, mr[i], xc[i]);
    }
    s = dpp_reduce(s);
    q = dpp_reduce(q);
    float var = fmaxf((q - s * s * (1.0f / Hh)) * (1.0f / (Hh - 1)), 0.f);
    float sdl = __builtin_amdgcn_sqrtf(var);
    const float sd = __builtin_bit_cast(
        float, __builtin_amdgcn_readlane(__builtin_bit_cast(int, sdl), 63));
    float sp[8];
#pragma unroll
    for (int i = 0; i < 8; ++i) {
      fire[i] = mr[i] >= fmaf(0.1f, sd, tac[i]);
      sp[i] = fire[i] ? 1.f : 0.f;
    }
    *(float4*)(base + (size_t)t * Hh + h0) = make_float4(sp[0], sp[1], sp[2], sp[3]);
    *(float4*)(base + (size_t)t * Hh + h1) = make_float4(sp[4], sp[5], sp[6], sp[7]);
  }
  float mf[8];
#pragma unroll
  for (int i = 0; i < 8; ++i) mf[i] = fire[i] ? 0.f : mr[i];
  *(float4*)(memout + (size_t)b * Hh + h0) = make_float4(mf[0], mf[1], mf[2], mf[3]);
  *(float4*)(memout + (size_t)b * Hh + h1) = make_float4(mf[4], mf[5], mf[6], mf[7]);
}

// -------------------------------------------------------------- launch ----
extern "C" void kernel_launch(void* const* d_in, const int* in_sizes, int n_in,
                              void* d_out, int out_size, void* d_ws,
                              size_t ws_size, hipStream_t stream) {
  const float* x    = (const float*)d_in[0];
  const float* W    = (const float*)d_in[1];
  const float* bias = (const float*)d_in[2];
  const float* ta   = (const float*)d_in[3];

  float* out    = (float*)d_out;
  float* spikes = out;
  float* memout = out + (size_t)Bb * T * Hh;

  if (ws_size >= 257 * sizeof(unsigned)) {
    unsigned* ws = (unsigned*)d_ws;
    zero_ws_kernel<<<dim3(1), dim3(512), 0, stream>>>(ws);
    fused_kernel<<<dim3(NBLOCKS), dim3(512), 0, stream>>>(
        x, W, bias, ta, spikes, memout, ws);
  } else {
    dim3 ggrid(Hh / 128, M / BM);
    gemm_kernel<<<ggrid, dim3(256), 0, stream>>>(x, W, bias, spikes);
    scan_kernel<<<dim3(Bb), dim3(64), 0, stream>>>(spikes, ta, memout);
  }
}